// Round 14
// baseline (773.356 us; speedup 1.0000x reference)
//
#include <hip/hip_runtime.h>

#define B_    1024
#define T_    256
#define LOCN  40001
#define E_    100
#define H_    100
#define NC    600   // [0,400): gates (i|f|g|o) preact, [400,500): t preact, [500,600): s preact

typedef float f32x2 __attribute__((ext_vector_type(2)));

// Fast sigmoid: rcp(1 + exp2(-x*log2e)). v_exp_f32 + v_rcp_f32 are ~1 ulp.
__device__ __forceinline__ float fsig(float x) {
    const float e = __builtin_amdgcn_exp2f(x * -1.442695040888963f);
    return __builtin_amdgcn_rcpf(1.f + e);
}

// ---------------------------------------------------------------------------
// Kernel 1: P_loc[LOC][600] = emb_loc @ [W_ih | W_xt | W_xs] + [b | b_t | b_s]
// ROUND-14: rebalance LDS vs VALU. R13 version: 4 cols/thread -> per k,
// 4 LDS b128 per 32 pk-FMA; per-CU LDS-cyc = 2x VALU-cyc (LDS-bound ~30 us).
// Balance needs cols=8: thread = (col-group cg of 8 cols, row-half rh of 8
// rows). Per k: 2 LDS b128 + 2 global W float4 + 32 pk-FMA -> LDS insts
// HALVED, LDS ~= VALU (~19 us each). The 500-boundary (500%8=4) is handled
// per-QUAD: each 4-col quad has its own (wp,stride,bias) -- quads never
// straddle (splits are x4). Per-column k-order unchanged -> bit-identical.
// proj_ts is folded in as one extra block (saves a launch).
// ---------------------------------------------------------------------------
constexpr int PROWS = 16;
constexpr int PPAD  = 20;   // 20 floats = 80 B row stride (16B-aligned, non-pow2)
constexpr int PB    = 256;
constexpr int NBLK  = (LOCN + PROWS - 1) / PROWS;   // 2501 tile blocks; block NBLK = ts

__global__ __launch_bounds__(PB) void proj_loc_kernel(
    const float* __restrict__ emb_loc,
    const float* __restrict__ W_ih,   // [100][400]
    const float* __restrict__ W_xt,   // [100][100]
    const float* __restrict__ W_xs,   // [100][100]
    const float* __restrict__ b,      // [400]
    const float* __restrict__ b_t,    // [100]
    const float* __restrict__ b_s,    // [100]
    const float* __restrict__ emb_t,  // [92][12]
    const float* __restrict__ emb_s,  // [92][12]
    const float* __restrict__ W_tt,   // [12][100]
    const float* __restrict__ W_ss,   // [12][100]
    float* __restrict__ P,            // [LOC][600]
    float* __restrict__ P_t,          // [92][100]
    float* __restrict__ P_s)          // [92][100]
{
    if (blockIdx.x == NBLK) {         // ---- fused proj_ts (one tiny block) ----
        for (int idx = threadIdx.x; idx < 2 * 92 * H_; idx += PB) {
            const int which = idx / (92 * H_);
            const int rem   = idx - which * (92 * H_);
            const int r = rem / H_, c = rem - r * H_;
            const float* e = which ? emb_s : emb_t;
            const float* W = which ? W_ss : W_tt;
            float acc = 0.f;
            #pragma unroll
            for (int k = 0; k < 12; ++k) acc += e[r * 12 + k] * W[k * H_ + c];
            (which ? P_s : P_t)[rem] = acc;
        }
        return;
    }

    __shared__ __attribute__((aligned(16))) float aT[E_][PPAD];  // transposed tile
    const int tid  = threadIdx.x;
    const int row0 = blockIdx.x * PROWS;

    for (int i = tid; i < PROWS * E_; i += PB) {
        const int r = i / E_, k = i - r * E_;
        const int rr = row0 + r;
        aT[k][r] = (rr < LOCN) ? emb_loc[rr * E_ + k] : 0.f;
    }
    __syncthreads();
    if (tid >= 150) return;

    const int rh = tid & 1;           // row half: rows rh*8 .. rh*8+8
    const int cg = tid >> 1;          // col group 0..74 -> cols cg*8 .. +8
    const int c  = cg * 8;
    const int r0 = rh * 8;

    // per-QUAD weight pointers (a quad of 4 cols never straddles a matrix)
    const float *wpA, *wpB, *bpA, *bpB; int strA, strB;
    {
        const int cA = c, cB = c + 4;
        if (cA < 400)      { wpA = W_ih + cA;         strA = 400; bpA = b   + cA;       }
        else if (cA < 500) { wpA = W_xt + (cA - 400); strA = 100; bpA = b_t + cA - 400; }
        else               { wpA = W_xs + (cA - 500); strA = 100; bpA = b_s + cA - 500; }
        if (cB < 400)      { wpB = W_ih + cB;         strB = 400; bpB = b   + cB;       }
        else if (cB < 500) { wpB = W_xt + (cB - 400); strB = 100; bpB = b_t + cB - 400; }
        else               { wpB = W_xs + (cB - 500); strB = 100; bpB = b_s + cB - 500; }
    }

    const float4 bA = *(const float4*)bpA;
    const float4 bB = *(const float4*)bpB;
    f32x2 aAl[8], aAh[8], aBl[8], aBh[8];   // rows x {colsA01,A23,B01,B23}
    #pragma unroll
    for (int r = 0; r < 8; ++r) {
        aAl[r] = (f32x2){bA.x, bA.y};
        aAh[r] = (f32x2){bA.z, bA.w};
        aBl[r] = (f32x2){bB.x, bB.y};
        aBh[r] = (f32x2){bB.z, bB.w};
    }

    #pragma unroll 2
    for (int k = 0; k < E_; ++k) {
        const float4 wA = *(const float4*)(wpA + (size_t)k * strA);
        const float4 wB = *(const float4*)(wpB + (size_t)k * strB);
        const f32x2 wA01 = {wA.x, wA.y}, wA23 = {wA.z, wA.w};
        const f32x2 wB01 = {wB.x, wB.y}, wB23 = {wB.z, wB.w};
        const float4 h0 = *(const float4*)(&aT[k][r0]);
        const float4 h1 = *(const float4*)(&aT[k][r0 + 4]);
        const float hs[8] = {h0.x, h0.y, h0.z, h0.w, h1.x, h1.y, h1.z, h1.w};
        #pragma unroll
        for (int r = 0; r < 8; ++r) {
            const f32x2 hh = {hs[r], hs[r]};
            aAl[r] = hh * wA01 + aAl[r];    // v_pk_fma_f32
            aAh[r] = hh * wA23 + aAh[r];
            aBl[r] = hh * wB01 + aBl[r];
            aBh[r] = hh * wB23 + aBh[r];
        }
    }

    #pragma unroll
    for (int r = 0; r < 8; ++r) {
        const int rr = row0 + r0 + r;
        if (rr < LOCN) {
            float4 o1, o2;
            o1.x = aAl[r].x; o1.y = aAl[r].y; o1.z = aAh[r].x; o1.w = aAh[r].y;
            o2.x = aBl[r].x; o2.y = aBl[r].y; o2.z = aBh[r].x; o2.w = aBh[r].y;
            *(float4*)(&P[(size_t)rr * NC + c])     = o1;
            *(float4*)(&P[(size_t)rr * NC + c + 4]) = o2;
        }
    }
}

// ---------------------------------------------------------------------------
// Kernel 3: the recurrence. BYTE-IDENTICAL to round 10/13 (619-635 us).
// Settled by R7-R12: VALU-count fixed (fsig + pk-FMA, ~277 VALU-us); every
// structural change (TLP, k-split, cc=2, LDS-W, latency staging, asm
// barriers) regressed -- this 2-barrier lockstep frame is the floor.
// ---------------------------------------------------------------------------
constexpr int RB = 4;
constexpr int NT = 704;

__global__ __launch_bounds__(NT, 3) void lstm_rec_kernel(
    const int* __restrict__ traj,
    const int* __restrict__ traj_len_p,
    const int* __restrict__ tu,      const int* __restrict__ tl,
    const int* __restrict__ tu_slot, const int* __restrict__ tl_slot,
    const int* __restrict__ su,      const int* __restrict__ sl,
    const int* __restrict__ su_slot, const int* __restrict__ sl_slot,
    const float* __restrict__ P,     // [LOC][600]
    const float* __restrict__ P_t,   // [92][100]
    const float* __restrict__ P_s,   // [92][100]
    const float* __restrict__ W_hh,  // [100][400]
    float* __restrict__ out)         // [B][100]
{
    __shared__ __attribute__((aligned(16))) float h_lds[RB][H_];
    __shared__ float gates_lds[RB][400];
    __shared__ float tg_lds[RB][H_];
    __shared__ float sg_lds[RB][H_];
    __shared__ int   loc_lds[2][RB];

    const int tid = threadIdx.x;
    const int b0  = blockIdx.x * RB;
    int steps = traj_len_p[0] + 1;
    if (steps > T_) steps = T_;

    // W_hh column -> register pairs (persist across all 256 steps)
    f32x2 w2[50];
    if (tid < 400) {
        #pragma unroll
        for (int j = 0; j < 50; ++j) {
            w2[j].x = W_hh[(2 * j)     * 400 + tid];
            w2[j].y = W_hh[(2 * j + 1) * 400 + tid];
        }
        ((float*)h_lds)[tid] = 0.f;
    }
    if (tid < RB) loc_lds[0][tid] = traj[(b0 + tid) * T_];

    const int er = tid / 100;        // epilogue row   (valid for tid<400)
    const int eh = tid - er * 100;   // epilogue h-idx
    float c_reg = 0.f, hval = 0.f;
    __syncthreads();

    for (int t = 0; t < steps; ++t) {
        const int buf = t & 1;

        if (tid >= 700) {                       // prefetch next step's locations
            int r = tid - 700;
            if (t + 1 < steps) loc_lds[buf ^ 1][r] = traj[(b0 + r) * T_ + t + 1];
        }

        if (tid < 400) {                        // ---- gates: gather + h @ W_hh ----
            const int n = tid;
            float gacc[RB];
            #pragma unroll
            for (int r = 0; r < RB; ++r) {
                const int loc = __builtin_amdgcn_readfirstlane(loc_lds[buf][r]);
                const float* __restrict__ Prow = P + (size_t)loc * NC;  // SGPR base
                gacc[r] = Prow[n];
            }

            f32x2 acc2[RB];
            #pragma unroll
            for (int r = 0; r < RB; ++r) acc2[r] = (f32x2){0.f, 0.f};
            #pragma unroll
            for (int k4 = 0; k4 < H_ / 4; ++k4) {
                #pragma unroll
                for (int r = 0; r < RB; ++r) {
                    const float4 hv = *(const float4*)(&h_lds[r][k4 * 4]);
                    const f32x2 hlo = {hv.x, hv.y};
                    const f32x2 hhi = {hv.z, hv.w};
                    acc2[r] = hlo * w2[2 * k4]     + acc2[r];   // v_pk_fma_f32
                    acc2[r] = hhi * w2[2 * k4 + 1] + acc2[r];   // v_pk_fma_f32
                }
            }
            const bool isg = (n >= 200 && n < 300);   // g-gate -> tanh via 2*sig(2x)-1
            #pragma unroll
            for (int r = 0; r < RB; ++r) {
                float v  = (acc2[r].x + acc2[r].y) + gacc[r];
                float xx = isg ? 2.f * v : v;
                float s  = fsig(xx);
                gates_lds[r][n] = isg ? (2.f * s - 1.f) : s;
            }
        }

        if (tid >= 448 && tid < 648) {          // ---- t/s gates (h-independent) ----
            const int  ch   = tid - 448;        // 0..199
            const bool is_t = ch < 100;
            const int  hx   = is_t ? ch : ch - 100;
            const int* up_a = is_t ? tu_slot : su_slot;
            const int* lo_a = is_t ? tl_slot : sl_slot;
            const int* ui_a = is_t ? tu : su;
            const int* li_a = is_t ? tl : sl;
            const float* Pq = is_t ? P_t : P_s;
            float* dst      = is_t ? &tg_lds[0][0] : &sg_lds[0][0];
            #pragma unroll
            for (int r = 0; r < RB; ++r) {
                const int off = __builtin_amdgcn_readfirstlane((b0 + r) * T_ + t);
                const int loc = __builtin_amdgcn_readfirstlane(loc_lds[buf][r]);
                const float* __restrict__ Prow = P + (size_t)loc * NC;  // SGPR base
                float gp  = Prow[400 + ch];
                float up  = (float)up_a[off];
                float low = (float)lo_a[off];
                int   ui  = ui_a[off], li = li_a[off];
                // interp @ W = (up*Pq[low_idx] + low*Pq[up_idx]) * rcp(max(up+low,1))
                const float inv = __builtin_amdgcn_rcpf(fmaxf(up + low, 1.f));
                float iv  = (up * Pq[li * H_ + hx] + low * Pq[ui * H_ + hx]) * inv;
                float pre = gp + iv;
                dst[r * H_ + hx] = fsig(pre);
            }
        }
        __syncthreads();

        if (tid < 400) {                        // ---- epilogue: c,h update ----
            float i_g = gates_lds[er][eh];
            float f_g = gates_lds[er][100 + eh];
            float g_g = gates_lds[er][200 + eh];
            float o_g = gates_lds[er][300 + eh];
            float tsg = tg_lds[er][eh] * sg_lds[er][eh];
            c_reg = f_g * c_reg + i_g * tsg * g_g;
            hval  = o_g * (2.f * fsig(2.f * c_reg) - 1.f);   // tanh = 2*sig(2x)-1
            h_lds[er][eh] = hval;
        }
        __syncthreads();
    }

    if (tid < 400) out[b0 * H_ + tid] = hval;
}

// ---------------------------------------------------------------------------
extern "C" void kernel_launch(void* const* d_in, const int* in_sizes, int n_in,
                              void* d_out, int out_size, void* d_ws, size_t ws_size,
                              hipStream_t stream) {
    const int*   traj     = (const int*)  d_in[0];
    // d_in[1] = lennew (unused by the reference)
    const int*   traj_len = (const int*)  d_in[2];
    const int*   tu       = (const int*)  d_in[3];
    const int*   tl       = (const int*)  d_in[4];
    const int*   tu_slot  = (const int*)  d_in[5];
    const int*   tl_slot  = (const int*)  d_in[6];
    const int*   su       = (const int*)  d_in[7];
    const int*   sl       = (const int*)  d_in[8];
    const int*   su_slot  = (const int*)  d_in[9];
    const int*   sl_slot  = (const int*)  d_in[10];
    const float* emb_loc  = (const float*)d_in[11];
    const float* emb_t    = (const float*)d_in[12];
    const float* emb_s    = (const float*)d_in[13];
    const float* W_ih     = (const float*)d_in[14];
    const float* W_hh     = (const float*)d_in[15];
    const float* b        = (const float*)d_in[16];
    const float* W_xt     = (const float*)d_in[17];
    const float* W_tt     = (const float*)d_in[18];
    const float* b_t      = (const float*)d_in[19];
    const float* W_xs     = (const float*)d_in[20];
    const float* W_ss     = (const float*)d_in[21];
    const float* b_s      = (const float*)d_in[22];

    float* P   = (float*)d_ws;              // 40001*600 = 24,000,600 floats (96.0 MB)
    float* P_t = P + (size_t)LOCN * NC;     // 9200 floats
    float* P_s = P_t + 92 * H_;             // 9200 floats

    proj_loc_kernel<<<NBLK + 1, PB, 0, stream>>>(
        emb_loc, W_ih, W_xt, W_xs, b, b_t, b_s,
        emb_t, emb_s, W_tt, W_ss, P, P_t, P_s);
    lstm_rec_kernel<<<B_ / RB, NT, 0, stream>>>(
        traj, traj_len, tu, tl, tu_slot, tl_slot, su, sl, su_slot, sl_slot,
        P, P_t, P_s, W_hh, (float*)d_out);
}

// Round 15
// 761.297 us; speedup vs baseline: 1.0158x; 1.0158x over previous
//
#include <hip/hip_runtime.h>

#define B_    1024
#define T_    256
#define LOCN  40001
#define E_    100
#define H_    100
#define NC    600   // [0,400): gates (i|f|g|o) preact, [400,500): t preact, [500,600): s preact

typedef float f32x2 __attribute__((ext_vector_type(2)));

// Fast sigmoid: rcp(1 + exp2(-x*log2e)). v_exp_f32 + v_rcp_f32 are ~1 ulp.
__device__ __forceinline__ float fsig(float x) {
    const float e = __builtin_amdgcn_exp2f(x * -1.442695040888963f);
    return __builtin_amdgcn_rcpf(1.f + e);
}

// ---------------------------------------------------------------------------
// Kernel 1: P_loc[LOC][600] = emb_loc @ [W_ih | W_xt | W_xs] + [b | b_t | b_s]
// ROUND-15: cols=8/thread (R14's correct LDS:VALU rebalance) WITHOUT R14's
// coalescing break. Each lane loads only its OWN quad cq = tid*4 (same
// fully-coalesced 16B-stride pattern as R13) and gets the partner quad via
// 4 shfl_xor(1) (pair is always intra-wave). No quad-selects: thread (cg,rh)
// accumulates rows rh*8..+8 x {own,partner} and writes to cq and cq^4 --
// the pair covers 16 rows x 8 cols exactly once. Per k: 1 coalesced W load
// + 4 shuffles + 2 LDS b128 (half of R13) + 32 pk-FMA. Per-column k-order
// unchanged -> bit-identical. proj_ts fused as one extra block.
// ---------------------------------------------------------------------------
constexpr int PROWS = 16;
constexpr int PPAD  = 20;   // 20 floats = 80 B row stride (16B-aligned, non-pow2)
constexpr int PB    = 256;
constexpr int NBLK  = (LOCN + PROWS - 1) / PROWS;   // 2501 tile blocks; block NBLK = ts

__global__ __launch_bounds__(PB) void proj_loc_kernel(
    const float* __restrict__ emb_loc,
    const float* __restrict__ W_ih,   // [100][400]
    const float* __restrict__ W_xt,   // [100][100]
    const float* __restrict__ W_xs,   // [100][100]
    const float* __restrict__ b,      // [400]
    const float* __restrict__ b_t,    // [100]
    const float* __restrict__ b_s,    // [100]
    const float* __restrict__ emb_t,  // [92][12]
    const float* __restrict__ emb_s,  // [92][12]
    const float* __restrict__ W_tt,   // [12][100]
    const float* __restrict__ W_ss,   // [12][100]
    float* __restrict__ P,            // [LOC][600]
    float* __restrict__ P_t,          // [92][100]
    float* __restrict__ P_s)          // [92][100]
{
    if (blockIdx.x == NBLK) {         // ---- fused proj_ts (one tiny block) ----
        for (int idx = threadIdx.x; idx < 2 * 92 * H_; idx += PB) {
            const int which = idx / (92 * H_);
            const int rem   = idx - which * (92 * H_);
            const int r = rem / H_, c = rem - r * H_;
            const float* e = which ? emb_s : emb_t;
            const float* W = which ? W_ss : W_tt;
            float acc = 0.f;
            #pragma unroll
            for (int k = 0; k < 12; ++k) acc += e[r * 12 + k] * W[k * H_ + c];
            (which ? P_s : P_t)[rem] = acc;
        }
        return;
    }

    __shared__ __attribute__((aligned(16))) float aT[E_][PPAD];  // transposed tile
    const int tid  = threadIdx.x;
    const int row0 = blockIdx.x * PROWS;

    for (int i = tid; i < PROWS * E_; i += PB) {
        const int r = i / E_, k = i - r * E_;
        const int rr = row0 + r;
        aT[k][r] = (rr < LOCN) ? emb_loc[rr * E_ + k] : 0.f;
    }
    __syncthreads();
    if (tid >= 150) return;

    const int rh = tid & 1;           // row half: rows rh*8 .. rh*8+8
    const int cq = tid * 4;           // OWN column quad (coalesced: 16B/lane)
    const int r0 = rh * 8;

    // own-quad weight pointer (a quad never straddles a matrix: splits are x4)
    const float *wpO, *bpO; int strO;
    if (cq < 400)      { wpO = W_ih + cq;         strO = 400; bpO = b   + cq;       }
    else if (cq < 500) { wpO = W_xt + (cq - 400); strO = 100; bpO = b_t + cq - 400; }
    else               { wpO = W_xs + (cq - 500); strO = 100; bpO = b_s + cq - 500; }

    // biases: own + partner (via intra-pair shuffle)
    const float4 bO = *(const float4*)bpO;
    float4 bP;
    bP.x = __shfl_xor(bO.x, 1); bP.y = __shfl_xor(bO.y, 1);
    bP.z = __shfl_xor(bO.z, 1); bP.w = __shfl_xor(bO.w, 1);

    f32x2 aOl[8], aOh[8], aPl[8], aPh[8];   // rows x {own01,own23,part01,part23}
    #pragma unroll
    for (int r = 0; r < 8; ++r) {
        aOl[r] = (f32x2){bO.x, bO.y};
        aOh[r] = (f32x2){bO.z, bO.w};
        aPl[r] = (f32x2){bP.x, bP.y};
        aPh[r] = (f32x2){bP.z, bP.w};
    }

    #pragma unroll 2
    for (int k = 0; k < E_; ++k) {
        const float4 wO = *(const float4*)(wpO + (size_t)k * strO);   // coalesced
        float4 wP;                                                     // partner quad
        wP.x = __shfl_xor(wO.x, 1); wP.y = __shfl_xor(wO.y, 1);
        wP.z = __shfl_xor(wO.z, 1); wP.w = __shfl_xor(wO.w, 1);
        const f32x2 wO01 = {wO.x, wO.y}, wO23 = {wO.z, wO.w};
        const f32x2 wP01 = {wP.x, wP.y}, wP23 = {wP.z, wP.w};
        const float4 h0 = *(const float4*)(&aT[k][r0]);
        const float4 h1 = *(const float4*)(&aT[k][r0 + 4]);
        const float hs[8] = {h0.x, h0.y, h0.z, h0.w, h1.x, h1.y, h1.z, h1.w};
        #pragma unroll
        for (int r = 0; r < 8; ++r) {
            const f32x2 hh = {hs[r], hs[r]};
            aOl[r] = hh * wO01 + aOl[r];    // v_pk_fma_f32
            aOh[r] = hh * wO23 + aOh[r];
            aPl[r] = hh * wP01 + aPl[r];
            aPh[r] = hh * wP23 + aPh[r];
        }
    }

    #pragma unroll
    for (int r = 0; r < 8; ++r) {
        const int rr = row0 + r0 + r;
        if (rr < LOCN) {
            float4 o1, o2;
            o1.x = aOl[r].x; o1.y = aOl[r].y; o1.z = aOh[r].x; o1.w = aOh[r].y;
            o2.x = aPl[r].x; o2.y = aPl[r].y; o2.z = aPh[r].x; o2.w = aPh[r].y;
            *(float4*)(&P[(size_t)rr * NC + cq])       = o1;   // own quad
            *(float4*)(&P[(size_t)rr * NC + (cq ^ 4)]) = o2;   // partner quad
        }
    }
}

// ---------------------------------------------------------------------------
// Kernel 3: the recurrence. BYTE-IDENTICAL to round 10/13/14 (619-635 us).
// Settled by R7-R12: VALU-count fixed (fsig + pk-FMA, ~277 VALU-us); every
// structural change (TLP, k-split, cc=2, LDS-W, latency staging, asm
// barriers) regressed -- this 2-barrier lockstep frame is the floor.
// ---------------------------------------------------------------------------
constexpr int RB = 4;
constexpr int NT = 704;

__global__ __launch_bounds__(NT, 3) void lstm_rec_kernel(
    const int* __restrict__ traj,
    const int* __restrict__ traj_len_p,
    const int* __restrict__ tu,      const int* __restrict__ tl,
    const int* __restrict__ tu_slot, const int* __restrict__ tl_slot,
    const int* __restrict__ su,      const int* __restrict__ sl,
    const int* __restrict__ su_slot, const int* __restrict__ sl_slot,
    const float* __restrict__ P,     // [LOC][600]
    const float* __restrict__ P_t,   // [92][100]
    const float* __restrict__ P_s,   // [92][100]
    const float* __restrict__ W_hh,  // [100][400]
    float* __restrict__ out)         // [B][100]
{
    __shared__ __attribute__((aligned(16))) float h_lds[RB][H_];
    __shared__ float gates_lds[RB][400];
    __shared__ float tg_lds[RB][H_];
    __shared__ float sg_lds[RB][H_];
    __shared__ int   loc_lds[2][RB];

    const int tid = threadIdx.x;
    const int b0  = blockIdx.x * RB;
    int steps = traj_len_p[0] + 1;
    if (steps > T_) steps = T_;

    // W_hh column -> register pairs (persist across all 256 steps)
    f32x2 w2[50];
    if (tid < 400) {
        #pragma unroll
        for (int j = 0; j < 50; ++j) {
            w2[j].x = W_hh[(2 * j)     * 400 + tid];
            w2[j].y = W_hh[(2 * j + 1) * 400 + tid];
        }
        ((float*)h_lds)[tid] = 0.f;
    }
    if (tid < RB) loc_lds[0][tid] = traj[(b0 + tid) * T_];

    const int er = tid / 100;        // epilogue row   (valid for tid<400)
    const int eh = tid - er * 100;   // epilogue h-idx
    float c_reg = 0.f, hval = 0.f;
    __syncthreads();

    for (int t = 0; t < steps; ++t) {
        const int buf = t & 1;

        if (tid >= 700) {                       // prefetch next step's locations
            int r = tid - 700;
            if (t + 1 < steps) loc_lds[buf ^ 1][r] = traj[(b0 + r) * T_ + t + 1];
        }

        if (tid < 400) {                        // ---- gates: gather + h @ W_hh ----
            const int n = tid;
            float gacc[RB];
            #pragma unroll
            for (int r = 0; r < RB; ++r) {
                const int loc = __builtin_amdgcn_readfirstlane(loc_lds[buf][r]);
                const float* __restrict__ Prow = P + (size_t)loc * NC;  // SGPR base
                gacc[r] = Prow[n];
            }

            f32x2 acc2[RB];
            #pragma unroll
            for (int r = 0; r < RB; ++r) acc2[r] = (f32x2){0.f, 0.f};
            #pragma unroll
            for (int k4 = 0; k4 < H_ / 4; ++k4) {
                #pragma unroll
                for (int r = 0; r < RB; ++r) {
                    const float4 hv = *(const float4*)(&h_lds[r][k4 * 4]);
                    const f32x2 hlo = {hv.x, hv.y};
                    const f32x2 hhi = {hv.z, hv.w};
                    acc2[r] = hlo * w2[2 * k4]     + acc2[r];   // v_pk_fma_f32
                    acc2[r] = hhi * w2[2 * k4 + 1] + acc2[r];   // v_pk_fma_f32
                }
            }
            const bool isg = (n >= 200 && n < 300);   // g-gate -> tanh via 2*sig(2x)-1
            #pragma unroll
            for (int r = 0; r < RB; ++r) {
                float v  = (acc2[r].x + acc2[r].y) + gacc[r];
                float xx = isg ? 2.f * v : v;
                float s  = fsig(xx);
                gates_lds[r][n] = isg ? (2.f * s - 1.f) : s;
            }
        }

        if (tid >= 448 && tid < 648) {          // ---- t/s gates (h-independent) ----
            const int  ch   = tid - 448;        // 0..199
            const bool is_t = ch < 100;
            const int  hx   = is_t ? ch : ch - 100;
            const int* up_a = is_t ? tu_slot : su_slot;
            const int* lo_a = is_t ? tl_slot : sl_slot;
            const int* ui_a = is_t ? tu : su;
            const int* li_a = is_t ? tl : sl;
            const float* Pq = is_t ? P_t : P_s;
            float* dst      = is_t ? &tg_lds[0][0] : &sg_lds[0][0];
            #pragma unroll
            for (int r = 0; r < RB; ++r) {
                const int off = __builtin_amdgcn_readfirstlane((b0 + r) * T_ + t);
                const int loc = __builtin_amdgcn_readfirstlane(loc_lds[buf][r]);
                const float* __restrict__ Prow = P + (size_t)loc * NC;  // SGPR base
                float gp  = Prow[400 + ch];
                float up  = (float)up_a[off];
                float low = (float)lo_a[off];
                int   ui  = ui_a[off], li = li_a[off];
                // interp @ W = (up*Pq[low_idx] + low*Pq[up_idx]) * rcp(max(up+low,1))
                const float inv = __builtin_amdgcn_rcpf(fmaxf(up + low, 1.f));
                float iv  = (up * Pq[li * H_ + hx] + low * Pq[ui * H_ + hx]) * inv;
                float pre = gp + iv;
                dst[r * H_ + hx] = fsig(pre);
            }
        }
        __syncthreads();

        if (tid < 400) {                        // ---- epilogue: c,h update ----
            float i_g = gates_lds[er][eh];
            float f_g = gates_lds[er][100 + eh];
            float g_g = gates_lds[er][200 + eh];
            float o_g = gates_lds[er][300 + eh];
            float tsg = tg_lds[er][eh] * sg_lds[er][eh];
            c_reg = f_g * c_reg + i_g * tsg * g_g;
            hval  = o_g * (2.f * fsig(2.f * c_reg) - 1.f);   // tanh = 2*sig(2x)-1
            h_lds[er][eh] = hval;
        }
        __syncthreads();
    }

    if (tid < 400) out[b0 * H_ + tid] = hval;
}

// ---------------------------------------------------------------------------
extern "C" void kernel_launch(void* const* d_in, const int* in_sizes, int n_in,
                              void* d_out, int out_size, void* d_ws, size_t ws_size,
                              hipStream_t stream) {
    const int*   traj     = (const int*)  d_in[0];
    // d_in[1] = lennew (unused by the reference)
    const int*   traj_len = (const int*)  d_in[2];
    const int*   tu       = (const int*)  d_in[3];
    const int*   tl       = (const int*)  d_in[4];
    const int*   tu_slot  = (const int*)  d_in[5];
    const int*   tl_slot  = (const int*)  d_in[6];
    const int*   su       = (const int*)  d_in[7];
    const int*   sl       = (const int*)  d_in[8];
    const int*   su_slot  = (const int*)  d_in[9];
    const int*   sl_slot  = (const int*)  d_in[10];
    const float* emb_loc  = (const float*)d_in[11];
    const float* emb_t    = (const float*)d_in[12];
    const float* emb_s    = (const float*)d_in[13];
    const float* W_ih     = (const float*)d_in[14];
    const float* W_hh     = (const float*)d_in[15];
    const float* b        = (const float*)d_in[16];
    const float* W_xt     = (const float*)d_in[17];
    const float* W_tt     = (const float*)d_in[18];
    const float* b_t      = (const float*)d_in[19];
    const float* W_xs     = (const float*)d_in[20];
    const float* W_ss     = (const float*)d_in[21];
    const float* b_s      = (const float*)d_in[22];

    float* P   = (float*)d_ws;              // 40001*600 = 24,000,600 floats (96.0 MB)
    float* P_t = P + (size_t)LOCN * NC;     // 9200 floats
    float* P_s = P_t + 92 * H_;             // 9200 floats

    proj_loc_kernel<<<NBLK + 1, PB, 0, stream>>>(
        emb_loc, W_ih, W_xt, W_xs, b, b_t, b_s,
        emb_t, emb_s, W_tt, W_ss, P, P_t, P_s);
    lstm_rec_kernel<<<B_ / RB, NT, 0, stream>>>(
        traj, traj_len, tu, tl, tu_slot, tl_slot, su, sl, su_slot, sl_slot,
        P, P_t, P_s, W_hh, (float*)d_out);
}

// Round 16
// 720.948 us; speedup vs baseline: 1.0727x; 1.0560x over previous
//
#include <hip/hip_runtime.h>

#define B_    1024
#define T_    256
#define LOCN  40001
#define E_    100
#define H_    100
#define NC    600   // [0,400): gates (i|f|g|o) preact, [400,500): t preact, [500,600): s preact

typedef float f32x2 __attribute__((ext_vector_type(2)));

// Fast sigmoid: rcp(1 + exp2(-x*log2e)). v_exp_f32 + v_rcp_f32 are ~1 ulp.
__device__ __forceinline__ float fsig(float x) {
    const float e = __builtin_amdgcn_exp2f(x * -1.442695040888963f);
    return __builtin_amdgcn_rcpf(1.f + e);
}

// ---------------------------------------------------------------------------
// Kernel 1: P_loc[LOC][600] = emb_loc @ [W_ih | W_xt | W_xs] + [b | b_t | b_s]
// EXACT round-13 version (measured best: residual 89 us vs 138-174 for all
// other variants). 4 cols/thread, coalesced W float4 loads, pk-FMA.
// R14/R15 post-mortem: this kernel is latency/occupancy-bound, NOT LDS-issue
// bound -- both "rebalance" attempts (strided loads / shuffle partner)
// regressed ~30-50 us. Do not touch.
// ---------------------------------------------------------------------------
constexpr int PROWS = 16;
constexpr int PPAD  = 20;   // 20 floats = 80 B row stride (16B-aligned, non-pow2)
constexpr int PB    = 256;

__global__ __launch_bounds__(PB) void proj_loc_kernel(
    const float* __restrict__ emb_loc,
    const float* __restrict__ W_ih,   // [100][400]
    const float* __restrict__ W_xt,   // [100][100]
    const float* __restrict__ W_xs,   // [100][100]
    const float* __restrict__ b,      // [400]
    const float* __restrict__ b_t,    // [100]
    const float* __restrict__ b_s,    // [100]
    float* __restrict__ P)            // [LOC][600]
{
    __shared__ __attribute__((aligned(16))) float aT[E_][PPAD];  // transposed tile
    const int tid  = threadIdx.x;
    const int row0 = blockIdx.x * PROWS;

    for (int i = tid; i < PROWS * E_; i += PB) {
        const int r = i / E_, k = i - r * E_;
        const int rr = row0 + r;
        aT[k][r] = (rr < LOCN) ? emb_loc[rr * E_ + k] : 0.f;
    }
    __syncthreads();
    if (tid >= 150) return;

    const int c = tid * 4;            // owned column quad
    const float* wp; int stride; const float* bp;
    if (c < 400)      { wp = W_ih + c;         stride = 400; bp = b   + c;       }
    else if (c < 500) { wp = W_xt + (c - 400); stride = 100; bp = b_t + c - 400; }
    else              { wp = W_xs + (c - 500); stride = 100; bp = b_s + c - 500; }

    const float4 bias = *(const float4*)bp;
    f32x2 a01[PROWS], a23[PROWS];     // cols (c,c+1) and (c+2,c+3) per row
    #pragma unroll
    for (int r = 0; r < PROWS; ++r) {
        a01[r] = (f32x2){bias.x, bias.y};
        a23[r] = (f32x2){bias.z, bias.w};
    }

    #pragma unroll 2
    for (int k = 0; k < E_; ++k) {
        const float4 wv = *(const float4*)(wp + (size_t)k * stride);
        const f32x2 w01 = {wv.x, wv.y};
        const f32x2 w23 = {wv.z, wv.w};
        #pragma unroll
        for (int r4 = 0; r4 < PROWS / 4; ++r4) {
            const float4 hv = *(const float4*)(&aT[k][r4 * 4]);
            const f32x2 h0 = {hv.x, hv.x};
            const f32x2 h1 = {hv.y, hv.y};
            const f32x2 h2 = {hv.z, hv.z};
            const f32x2 h3 = {hv.w, hv.w};
            a01[r4 * 4 + 0] = h0 * w01 + a01[r4 * 4 + 0];   // v_pk_fma_f32
            a23[r4 * 4 + 0] = h0 * w23 + a23[r4 * 4 + 0];
            a01[r4 * 4 + 1] = h1 * w01 + a01[r4 * 4 + 1];
            a23[r4 * 4 + 1] = h1 * w23 + a23[r4 * 4 + 1];
            a01[r4 * 4 + 2] = h2 * w01 + a01[r4 * 4 + 2];
            a23[r4 * 4 + 2] = h2 * w23 + a23[r4 * 4 + 2];
            a01[r4 * 4 + 3] = h3 * w01 + a01[r4 * 4 + 3];
            a23[r4 * 4 + 3] = h3 * w23 + a23[r4 * 4 + 3];
        }
    }

    #pragma unroll
    for (int r = 0; r < PROWS; ++r) {
        const int rr = row0 + r;
        if (rr < LOCN) {
            float4 o;
            o.x = a01[r].x; o.y = a01[r].y; o.z = a23[r].x; o.w = a23[r].y;
            *(float4*)(&P[(size_t)rr * NC + c]) = o;
        }
    }
}

// ---------------------------------------------------------------------------
// Kernel 2: P_t[92][100] = emb_t @ W_tt ; P_s[92][100] = emb_s @ W_ss
// ---------------------------------------------------------------------------
__global__ void proj_ts_kernel(
    const float* __restrict__ emb_t, const float* __restrict__ emb_s,
    const float* __restrict__ W_tt,  const float* __restrict__ W_ss,
    float* __restrict__ P_t, float* __restrict__ P_s)
{
    int idx = blockIdx.x * 256 + threadIdx.x;
    if (idx >= 2 * 92 * H_) return;
    int which = idx / (92 * H_);
    int rem   = idx - which * (92 * H_);
    int r = rem / H_, c = rem - r * H_;
    const float* e = which ? emb_s : emb_t;
    const float* W = which ? W_ss : W_tt;
    float acc = 0.f;
    #pragma unroll
    for (int k = 0; k < 12; ++k) acc += e[r * 12 + k] * W[k * H_ + c];
    (which ? P_s : P_t)[rem] = acc;
}

// ---------------------------------------------------------------------------
// Kernel 3: the recurrence. BYTE-IDENTICAL to rounds 10/13/14/15 (619-635 us
// band). Settled by R7-R12: VALU-count fixed (fsig + pk-FMA, ~277 VALU-us);
// every structural change (TLP, k-split, cc=2, LDS-W, latency staging, asm
// barriers) regressed -- this 2-barrier lockstep frame is the floor.
// ---------------------------------------------------------------------------
constexpr int RB = 4;
constexpr int NT = 704;

__global__ __launch_bounds__(NT, 3) void lstm_rec_kernel(
    const int* __restrict__ traj,
    const int* __restrict__ traj_len_p,
    const int* __restrict__ tu,      const int* __restrict__ tl,
    const int* __restrict__ tu_slot, const int* __restrict__ tl_slot,
    const int* __restrict__ su,      const int* __restrict__ sl,
    const int* __restrict__ su_slot, const int* __restrict__ sl_slot,
    const float* __restrict__ P,     // [LOC][600]
    const float* __restrict__ P_t,   // [92][100]
    const float* __restrict__ P_s,   // [92][100]
    const float* __restrict__ W_hh,  // [100][400]
    float* __restrict__ out)         // [B][100]
{
    __shared__ __attribute__((aligned(16))) float h_lds[RB][H_];
    __shared__ float gates_lds[RB][400];
    __shared__ float tg_lds[RB][H_];
    __shared__ float sg_lds[RB][H_];
    __shared__ int   loc_lds[2][RB];

    const int tid = threadIdx.x;
    const int b0  = blockIdx.x * RB;
    int steps = traj_len_p[0] + 1;
    if (steps > T_) steps = T_;

    // W_hh column -> register pairs (persist across all 256 steps)
    f32x2 w2[50];
    if (tid < 400) {
        #pragma unroll
        for (int j = 0; j < 50; ++j) {
            w2[j].x = W_hh[(2 * j)     * 400 + tid];
            w2[j].y = W_hh[(2 * j + 1) * 400 + tid];
        }
        ((float*)h_lds)[tid] = 0.f;
    }
    if (tid < RB) loc_lds[0][tid] = traj[(b0 + tid) * T_];

    const int er = tid / 100;        // epilogue row   (valid for tid<400)
    const int eh = tid - er * 100;   // epilogue h-idx
    float c_reg = 0.f, hval = 0.f;
    __syncthreads();

    for (int t = 0; t < steps; ++t) {
        const int buf = t & 1;

        if (tid >= 700) {                       // prefetch next step's locations
            int r = tid - 700;
            if (t + 1 < steps) loc_lds[buf ^ 1][r] = traj[(b0 + r) * T_ + t + 1];
        }

        if (tid < 400) {                        // ---- gates: gather + h @ W_hh ----
            const int n = tid;
            float gacc[RB];
            #pragma unroll
            for (int r = 0; r < RB; ++r) {
                const int loc = __builtin_amdgcn_readfirstlane(loc_lds[buf][r]);
                const float* __restrict__ Prow = P + (size_t)loc * NC;  // SGPR base
                gacc[r] = Prow[n];
            }

            f32x2 acc2[RB];
            #pragma unroll
            for (int r = 0; r < RB; ++r) acc2[r] = (f32x2){0.f, 0.f};
            #pragma unroll
            for (int k4 = 0; k4 < H_ / 4; ++k4) {
                #pragma unroll
                for (int r = 0; r < RB; ++r) {
                    const float4 hv = *(const float4*)(&h_lds[r][k4 * 4]);
                    const f32x2 hlo = {hv.x, hv.y};
                    const f32x2 hhi = {hv.z, hv.w};
                    acc2[r] = hlo * w2[2 * k4]     + acc2[r];   // v_pk_fma_f32
                    acc2[r] = hhi * w2[2 * k4 + 1] + acc2[r];   // v_pk_fma_f32
                }
            }
            const bool isg = (n >= 200 && n < 300);   // g-gate -> tanh via 2*sig(2x)-1
            #pragma unroll
            for (int r = 0; r < RB; ++r) {
                float v  = (acc2[r].x + acc2[r].y) + gacc[r];
                float xx = isg ? 2.f * v : v;
                float s  = fsig(xx);
                gates_lds[r][n] = isg ? (2.f * s - 1.f) : s;
            }
        }

        if (tid >= 448 && tid < 648) {          // ---- t/s gates (h-independent) ----
            const int  ch   = tid - 448;        // 0..199
            const bool is_t = ch < 100;
            const int  hx   = is_t ? ch : ch - 100;
            const int* up_a = is_t ? tu_slot : su_slot;
            const int* lo_a = is_t ? tl_slot : sl_slot;
            const int* ui_a = is_t ? tu : su;
            const int* li_a = is_t ? tl : sl;
            const float* Pq = is_t ? P_t : P_s;
            float* dst      = is_t ? &tg_lds[0][0] : &sg_lds[0][0];
            #pragma unroll
            for (int r = 0; r < RB; ++r) {
                const int off = __builtin_amdgcn_readfirstlane((b0 + r) * T_ + t);
                const int loc = __builtin_amdgcn_readfirstlane(loc_lds[buf][r]);
                const float* __restrict__ Prow = P + (size_t)loc * NC;  // SGPR base
                float gp  = Prow[400 + ch];
                float up  = (float)up_a[off];
                float low = (float)lo_a[off];
                int   ui  = ui_a[off], li = li_a[off];
                // interp @ W = (up*Pq[low_idx] + low*Pq[up_idx]) * rcp(max(up+low,1))
                const float inv = __builtin_amdgcn_rcpf(fmaxf(up + low, 1.f));
                float iv  = (up * Pq[li * H_ + hx] + low * Pq[ui * H_ + hx]) * inv;
                float pre = gp + iv;
                dst[r * H_ + hx] = fsig(pre);
            }
        }
        __syncthreads();

        if (tid < 400) {                        // ---- epilogue: c,h update ----
            float i_g = gates_lds[er][eh];
            float f_g = gates_lds[er][100 + eh];
            float g_g = gates_lds[er][200 + eh];
            float o_g = gates_lds[er][300 + eh];
            float tsg = tg_lds[er][eh] * sg_lds[er][eh];
            c_reg = f_g * c_reg + i_g * tsg * g_g;
            hval  = o_g * (2.f * fsig(2.f * c_reg) - 1.f);   // tanh = 2*sig(2x)-1
            h_lds[er][eh] = hval;
        }
        __syncthreads();
    }

    if (tid < 400) out[b0 * H_ + tid] = hval;
}

// ---------------------------------------------------------------------------
extern "C" void kernel_launch(void* const* d_in, const int* in_sizes, int n_in,
                              void* d_out, int out_size, void* d_ws, size_t ws_size,
                              hipStream_t stream) {
    const int*   traj     = (const int*)  d_in[0];
    // d_in[1] = lennew (unused by the reference)
    const int*   traj_len = (const int*)  d_in[2];
    const int*   tu       = (const int*)  d_in[3];
    const int*   tl       = (const int*)  d_in[4];
    const int*   tu_slot  = (const int*)  d_in[5];
    const int*   tl_slot  = (const int*)  d_in[6];
    const int*   su       = (const int*)  d_in[7];
    const int*   sl       = (const int*)  d_in[8];
    const int*   su_slot  = (const int*)  d_in[9];
    const int*   sl_slot  = (const int*)  d_in[10];
    const float* emb_loc  = (const float*)d_in[11];
    const float* emb_t    = (const float*)d_in[12];
    const float* emb_s    = (const float*)d_in[13];
    const float* W_ih     = (const float*)d_in[14];
    const float* W_hh     = (const float*)d_in[15];
    const float* b        = (const float*)d_in[16];
    const float* W_xt     = (const float*)d_in[17];
    const float* W_tt     = (const float*)d_in[18];
    const float* b_t      = (const float*)d_in[19];
    const float* W_xs     = (const float*)d_in[20];
    const float* W_ss     = (const float*)d_in[21];
    const float* b_s      = (const float*)d_in[22];

    float* P   = (float*)d_ws;              // 40001*600 = 24,000,600 floats (96.0 MB)
    float* P_t = P + (size_t)LOCN * NC;     // 9200 floats
    float* P_s = P_t + 92 * H_;             // 9200 floats

    proj_loc_kernel<<<(LOCN + PROWS - 1) / PROWS, PB, 0, stream>>>(
        emb_loc, W_ih, W_xt, W_xs, b, b_t, b_s, P);
    proj_ts_kernel<<<(2 * 92 * H_ + 255) / 256, 256, 0, stream>>>(
        emb_t, emb_s, W_tt, W_ss, P_t, P_s);
    lstm_rec_kernel<<<B_ / RB, NT, 0, stream>>>(
        traj, traj_len, tu, tl, tu_slot, tl_slot, su, sl, su_slot, sl_slot,
        P, P_t, P_s, W_hh, (float*)d_out);
}